// Round 18
// baseline (448.269 us; speedup 1.0000x reference)
//
#include <hip/hip_runtime.h>
#include <math.h>

#define N_NODES 50000
#define N_EDGES 800000
#define HD 128          // H*D = 4*32
#define GG 1024
#define NEG_SLOPE 0.2f
#define SCAN_B 1024
#define NB ((N_NODES + SCAN_B - 1) / SCAN_B)   // 49
#define NXV4 800000                            // x float4 count (N*64/4)
#define NWCONV 81920                           // W-convert thread count

typedef __attribute__((ext_vector_type(8))) short bf16x8;
typedef __attribute__((ext_vector_type(4))) float f32x4;
typedef __attribute__((ext_vector_type(2))) float f32x2;

__device__ __forceinline__ unsigned short f2bf(float v) {
    unsigned u = __float_as_uint(v);
    u += 0x7fff + ((u >> 16) & 1);       // round-to-nearest-even
    return (unsigned short)(u >> 16);
}
__device__ __forceinline__ float bf2f(unsigned short s) {
    return __uint_as_float((unsigned)s << 16);
}

// ------- fused conversions + deg-hist + gptr (deg zeroed by memset beforehand)
__global__ void convert_prep(const float* __restrict__ x,
                             unsigned short* __restrict__ Xh, unsigned short* __restrict__ Xl,
                             const float* __restrict__ W0l, const float* __restrict__ W0r,
                             const float* __restrict__ W1l, const float* __restrict__ W1r,
                             const float* __restrict__ W2l, const float* __restrict__ W2r,
                             unsigned short* __restrict__ Wth, unsigned short* __restrict__ Wtl,
                             const int* __restrict__ dst, int* __restrict__ deg,
                             const int* __restrict__ batch, int* __restrict__ gptr)
{
    const int i = blockIdx.x * 256 + threadIdx.x;
    if (i < NXV4) {
        const float4 v = *(const float4*)(x + (size_t)i * 4);
        ushort4 h, lo;
        h.x = f2bf(v.x); lo.x = f2bf(v.x - bf2f(h.x));
        h.y = f2bf(v.y); lo.y = f2bf(v.y - bf2f(h.y));
        h.z = f2bf(v.z); lo.z = f2bf(v.z - bf2f(h.z));
        h.w = f2bf(v.w); lo.w = f2bf(v.w - bf2f(h.w));
        *(ushort4*)(Xh + (size_t)i * 4) = h;
        *(ushort4*)(Xl + (size_t)i * 4) = lo;
        return;
    }
    if (i < NXV4 + NWCONV) {
        const int t = i - NXV4;
        const float* Wl; const float* Wr;
        int c, k, o;
        if (t < 16384) {                       // layer 0, K=64
            c = t >> 6; k = t & 63; o = t;
            Wl = W0l; Wr = W0r;
        } else if (t < 49152) {                // layer 1, K=128
            const int b = t - 16384; c = b >> 7; k = b & 127; o = 32768 + b;
            Wl = W1l; Wr = W1r;
        } else {                               // layer 2, K=128
            const int b = t - 49152; c = b >> 7; k = b & 127; o = 65536 + b;
            Wl = W2l; Wr = W2r;
        }
        const float v = (c < 128) ? Wl[(size_t)k * 128 + c] : Wr[(size_t)k * 128 + (c - 128)];
        const unsigned short hi = f2bf(v);
        Wth[o] = hi;
        Wtl[o] = f2bf(v - bf2f(hi));
        return;
    }
    const int e = i - NXV4 - NWCONV;
    if (e < N_EDGES) atomicAdd(&deg[dst[e]], 1);
    if (e > N_NODES) return;
    if (e == 0) {
        for (int g = 0; g <= batch[0]; g++) gptr[g] = 0;
    } else if (e == N_NODES) {
        for (int g = batch[N_NODES - 1] + 1; g <= GG; g++) gptr[g] = N_NODES;
    } else {
        const int b0 = batch[e - 1], b1 = batch[e];
        for (int g = b0 + 1; g <= b1; g++) gptr[g] = e;
    }
}

// ---------------------------------------------------------------- CSR scan
__launch_bounds__(SCAN_B)
__global__ void scan_block(const int* __restrict__ deg, int* __restrict__ rowptr,
                           int* __restrict__ btot)
{
    __shared__ int s[SCAN_B];
    const int tid = threadIdx.x;
    const int i = blockIdx.x * SCAN_B + tid;
    int v = (i < N_NODES) ? deg[i] : 0;
    s[tid] = v;
    __syncthreads();
    for (int off = 1; off < SCAN_B; off <<= 1) {
        int t = (tid >= off) ? s[tid - off] : 0;
        __syncthreads();
        s[tid] += t;
        __syncthreads();
    }
    if (i < N_NODES) rowptr[i] = s[tid] - v;
    if (tid == SCAN_B - 1) btot[blockIdx.x] = s[SCAN_B - 1];
}

__launch_bounds__(256)
__global__ void scan_add(const int* __restrict__ btot, int* __restrict__ rowptr,
                         int* __restrict__ cursor)
{
    __shared__ int sb[NB + 1];
    const int tid = threadIdx.x;
    if (tid < 64) {
        const int v = (tid < NB) ? btot[tid] : 0;
        int incl = v;
        #pragma unroll
        for (int off = 1; off < 64; off <<= 1) {
            const int t = __shfl_up(incl, off);
            if (tid >= off) incl += t;
        }
        if (tid < NB) sb[tid] = incl - v;      // exclusive prefix
        if (tid == NB - 1) sb[NB] = incl;      // total
    }
    __syncthreads();
    const int i = blockIdx.x * 256 + tid;
    if (i < N_NODES) {
        const int r = rowptr[i] + sb[i >> 10];
        rowptr[i] = r;
        cursor[i] = r;
    }
    if (i == N_NODES) rowptr[N_NODES] = sb[NB];
}

__global__ void scatter_csr(const int* __restrict__ src, const int* __restrict__ dst,
                            int* __restrict__ cursor, int* __restrict__ csr_src)
{
    int e = blockIdx.x * 256 + threadIdx.x;
    if (e >= N_EDGES) return;
    int pos = atomicAdd(&cursor[dst[e]], 1);
    csr_src[pos] = src[e];
}

// --------------------------------------------- persistent LDS-A MFMA dual GEMM
// (R11-proven config: 4 waves/block, 256 thr, grid 512 = 2 col-groups x 256 streams)
template<int K>
__launch_bounds__(256)
__global__ void gemm_lds(const unsigned short* __restrict__ Xh, const unsigned short* __restrict__ Xl,
                         const unsigned short* __restrict__ Wth, const unsigned short* __restrict__ Wtl,
                         const float* __restrict__ bl, const float* __restrict__ br,
                         float* __restrict__ Cl, float* __restrict__ Cr, int n)
{
    constexpr int NCH = K / 32;
    constexpr int STR = K + 8;
    constexpr int RT  = (N_NODES + 63) / 64;   // 782 row tiles
    __shared__ unsigned short AsH[64 * STR], AsL[64 * STR];
    const int tid  = threadIdx.x;
    const int wave = tid >> 6;
    const int lane = tid & 63;
    const int quad = lane >> 4;
    const int l15  = lane & 15;
    const int cg   = blockIdx.x & 1;           // col group
    const int rs   = blockIdx.x >> 1;          // row stream
    const int NS   = gridDim.x >> 1;
    const int colid = cg * 4 + wave;           // 0..7
    const int cb32  = colid * 32;

    // B fragments resident for the whole kernel
    bf16x8 Bh[NCH][2], Bo[NCH][2];
    #pragma unroll
    for (int ch = 0; ch < NCH; ch++)
        #pragma unroll
        for (int nt = 0; nt < 2; nt++) {
            const size_t wo = (size_t)(cb32 + nt * 16 + l15) * K + ch * 32 + quad * 8;
            Bh[ch][nt] = *(const bf16x8*)(Wth + wo);
            Bo[ch][nt] = *(const bf16x8*)(Wtl + wo);
        }

    const int cb = cb32 & 127;
    const float* bias = (colid < 4) ? bl : br;
    float* C = (colid < 4) ? Cl : Cr;
    const float bv0 = bias[cb + l15];
    const float bv1 = bias[cb + 16 + l15];

    for (int rt = rs; rt < RT; rt += NS) {
        const int row0 = rt * 64;
        // stage A tile: 64 rows x K (hi+lo), coalesced 16B per thread
        {
            constexpr int THR = K / 8;             // threads per row
            constexpr int RPP = 256 / THR;         // rows per pass
            const int sr = tid / THR, seg = tid % THR;
            #pragma unroll
            for (int ps = 0; ps < 64 / RPP; ps++) {
                const int r = ps * RPP + sr;
                int gr = row0 + r;
                gr = (gr < n) ? gr : (n - 1);      // clamp: dup rows never stored
                const size_t go = (size_t)gr * K + seg * 8;
                *(uint4*)&AsH[r * STR + seg * 8] = *(const uint4*)(Xh + go);
                *(uint4*)&AsL[r * STR + seg * 8] = *(const uint4*)(Xl + go);
            }
        }
        __syncthreads();

        f32x4 acc[4][2];
        #pragma unroll
        for (int mt = 0; mt < 4; mt++) {
            acc[mt][0] = (f32x4){0.f, 0.f, 0.f, 0.f};
            acc[mt][1] = (f32x4){0.f, 0.f, 0.f, 0.f};
        }
        #pragma unroll
        for (int ch = 0; ch < NCH; ch++) {
            bf16x8 ah[4], al[4];
            #pragma unroll
            for (int mt = 0; mt < 4; mt++) {
                ah[mt] = *(const bf16x8*)&AsH[(mt * 16 + l15) * STR + ch * 32 + quad * 8];
                al[mt] = *(const bf16x8*)&AsL[(mt * 16 + l15) * STR + ch * 32 + quad * 8];
            }
            #pragma unroll
            for (int nt = 0; nt < 2; nt++)
                #pragma unroll
                for (int mt = 0; mt < 4; mt++) {
                    acc[mt][nt] = __builtin_amdgcn_mfma_f32_16x16x32_bf16(ah[mt], Bh[ch][nt], acc[mt][nt], 0, 0, 0);
                    acc[mt][nt] = __builtin_amdgcn_mfma_f32_16x16x32_bf16(ah[mt], Bo[ch][nt], acc[mt][nt], 0, 0, 0);
                    acc[mt][nt] = __builtin_amdgcn_mfma_f32_16x16x32_bf16(al[mt], Bh[ch][nt], acc[mt][nt], 0, 0, 0);
                }
        }

        // epilogue: C/D layout col=lane&15, row=quad*4+reg [m89-verified]
        #pragma unroll
        for (int nt = 0; nt < 2; nt++) {
            const float bv = nt ? bv1 : bv0;
            #pragma unroll
            for (int mt = 0; mt < 4; mt++)
                #pragma unroll
                for (int r = 0; r < 4; r++) {
                    const int row = row0 + mt * 16 + quad * 4 + r;
                    if (row < n)
                        C[(size_t)row * 128 + cb + nt * 16 + l15] = acc[mt][nt][r] + bv;
                }
        }
        __syncthreads();    // LDS reuse fence before next stage
    }
}

// ------------------------------------------------- fused per-node attention
// one wave per dst node, FOUR edges in flight (4 groups x 16 lanes, 8 dims/lane).
// PER-HEAD softmax: head = 4-lane cluster; score reduce over xor 1,2 ONLY.
// DEPTH-2 gather prefetch (vp/np/qp triple buffer): load issues 2 iterations
// ahead of use to cover L2-miss latency. Same edge order, same numerics.
// LAST=1: per-node h.Wh written to pernode[node] (plain store, no atomics).
template<int LAST>
__launch_bounds__(256)
__global__ void node_attn(const float* __restrict__ xl, const float* __restrict__ xr,
                          const int* __restrict__ rowptr, const int* __restrict__ csr_src,
                          const float* __restrict__ att, const float* __restrict__ bvec,
                          unsigned short* __restrict__ Hh, unsigned short* __restrict__ Hl,
                          const float* __restrict__ Wh, float* __restrict__ pernode)
{
    const int node = (blockIdx.x * 256 + threadIdx.x) >> 6;
    const int lane = threadIdx.x & 63;
    if (node >= N_NODES) return;
    const int grp = lane >> 4;     // 4 edge slots
    const int li  = lane & 15;     // 16 lanes per edge, 8 dims each; head = li>>2

    const size_t nb = (size_t)node * HD + li * 8;
    f32x2 xrp[4], awp[4];
    {
        const float4 a = *(const float4*)(xr + nb);
        const float4 b = *(const float4*)(xr + nb + 4);
        xrp[0] = (f32x2){a.x, a.y}; xrp[1] = (f32x2){a.z, a.w};
        xrp[2] = (f32x2){b.x, b.y}; xrp[3] = (f32x2){b.z, b.w};
        const float4 c = *(const float4*)(att + li * 8);
        const float4 d = *(const float4*)(att + li * 8 + 4);
        awp[0] = (f32x2){c.x, c.y}; awp[1] = (f32x2){c.z, c.w};
        awp[2] = (f32x2){d.x, d.y}; awp[3] = (f32x2){d.z, d.w};
    }
    const f32x2 nsl = (f32x2){NEG_SLOPE, NEG_SLOPE};
    const int beg = rowptr[node];
    const int end = rowptr[node + 1];

    float m = -1e30f, l = 0.f;
    f32x2 accp[4];
    #pragma unroll
    for (int j = 0; j < 4; j++) accp[j] = (f32x2){0.f, 0.f};

#define LOADV(vv, eidx)                                                        \
    {                                                                          \
        const int _e = (eidx);                                                 \
        const int _s = (_e < end) ? csr_src[_e] : 0;                           \
        const float4 _a = *(const float4*)(xl + (size_t)_s * HD + li * 8);     \
        const float4 _b = *(const float4*)(xl + (size_t)_s * HD + li * 8 + 4); \
        vv[0] = (f32x2){_a.x, _a.y}; vv[1] = (f32x2){_a.z, _a.w};              \
        vv[2] = (f32x2){_b.x, _b.y}; vv[3] = (f32x2){_b.z, _b.w};              \
    }

    // prologue: depth-2 prefetch
    f32x2 vp[4], np[4], qp[4];
    LOADV(vp, beg + grp);
    #pragma unroll
    for (int j = 0; j < 4; j++) np[j] = vp[j];
    if (beg + 4 < end) LOADV(np, beg + 4 + grp);

    for (int base = beg; base < end; base += 4) {
        const bool valid = (base + grp) < end;
        // issue the load 2 iterations ahead (into qp)
        #pragma unroll
        for (int j = 0; j < 4; j++) qp[j] = np[j];
        if (base + 8 < end) LOADV(qp, base + 8 + grp);
        // leaky_relu(v + xr) . att  -- two independent f32x2 chains
        f32x2 pd0 = (f32x2){0.f, 0.f}, pd1 = (f32x2){0.f, 0.f};
        #pragma unroll
        for (int j = 0; j < 4; j++) {
            f32x2 t = vp[j] + xrp[j];
            const f32x2 u = t * nsl;
            t[0] = fmaxf(t[0], u[0]);
            t[1] = fmaxf(t[1], u[1]);
            if (j & 1) pd1 = t * awp[j] + pd1;
            else       pd0 = t * awp[j] + pd0;
        }
        const f32x2 pds = pd0 + pd1;
        float p = pds[0] + pds[1];
        // per-head score: 4-lane cluster (32 dims) -> xor 1,2 only
        p += __shfl_xor(p, 1);
        p += __shfl_xor(p, 2);

        const float mn = valid ? fmaxf(m, p) : m;
        const float w  = valid ? __expf(p - mn) : 0.f;
        const float sc = __expf(m - mn);
        l = fmaf(l, sc, w);
        const f32x2 w2  = (f32x2){w, w};
        const f32x2 sc2 = (f32x2){sc, sc};
        #pragma unroll
        for (int j = 0; j < 4; j++) {
            accp[j] = accp[j] * sc2 + w2 * vp[j];
            vp[j] = np[j];
            np[j] = qp[j];
        }
        m = mn;
    }
#undef LOADV

    // cross-group merge (xor 16, then 32): same li (same head/dims), different group
    #pragma unroll
    for (int off = 16; off < 64; off <<= 1) {
        const float mo = __shfl_xor(m, off);
        const float lo = __shfl_xor(l, off);
        f32x2 bo[4];
        #pragma unroll
        for (int j = 0; j < 4; j++) {
            bo[j][0] = __shfl_xor(accp[j][0], off);
            bo[j][1] = __shfl_xor(accp[j][1], off);
        }
        const float mm = fmaxf(m, mo);
        const float e1 = __expf(m - mm);
        const float e2 = __expf(mo - mm);
        l = l * e1 + lo * e2;
        const f32x2 e1p = (f32x2){e1, e1};
        const f32x2 e2p = (f32x2){e2, e2};
        #pragma unroll
        for (int j = 0; j < 4; j++)
            accp[j] = accp[j] * e1p + bo[j] * e2p;
        m = mm;
    }

    if (grp == 0) {
        const float inv = (l > 0.f) ? 1.f / l : 0.f;   // per-head l (per lane)
        const float4 bb0 = *(const float4*)(bvec + li * 8);
        const float4 bb1 = *(const float4*)(bvec + li * 8 + 4);
        float o[8];
        o[0] = fmaf(accp[0][0], inv, bb0.x);
        o[1] = fmaf(accp[0][1], inv, bb0.y);
        o[2] = fmaf(accp[1][0], inv, bb0.z);
        o[3] = fmaf(accp[1][1], inv, bb0.w);
        o[4] = fmaf(accp[2][0], inv, bb1.x);
        o[5] = fmaf(accp[2][1], inv, bb1.y);
        o[6] = fmaf(accp[3][0], inv, bb1.z);
        o[7] = fmaf(accp[3][1], inv, bb1.w);
        #pragma unroll
        for (int j = 0; j < 8; j++)
            o[j] = (o[j] > 0.f) ? o[j] : expm1f(o[j]);
        if (LAST) {
            // fused head: d = h . Wh, deterministic per-node store (no atomics)
            const float4 w0 = *(const float4*)(Wh + li * 8);
            const float4 w1 = *(const float4*)(Wh + li * 8 + 4);
            float da = o[0] * w0.x + o[2] * w0.z;
            float db = o[1] * w0.y + o[3] * w0.w;
            da = fmaf(o[4], w1.x, da); db = fmaf(o[5], w1.y, db);
            da = fmaf(o[6], w1.z, da); db = fmaf(o[7], w1.w, db);
            float d = da + db;
            d += __shfl_xor(d, 1);
            d += __shfl_xor(d, 2);
            d += __shfl_xor(d, 4);
            d += __shfl_xor(d, 8);
            if (li == 0) pernode[node] = d;
        } else {
            bf16x8 hv, lv;
            #pragma unroll
            for (int j = 0; j < 8; j++) {
                unsigned short h = f2bf(o[j]);
                hv[j] = (short)h;
                lv[j] = (short)f2bf(o[j] - bf2f(h));
            }
            *(bf16x8*)(Hh + nb) = hv;
            *(bf16x8*)(Hl + nb) = lv;
        }
    }
}

// ------------------------------------------ head finish: one wave per graph
__launch_bounds__(256)
__global__ void finish_head(const float* __restrict__ pernode, const int* __restrict__ gptr,
                            const float* __restrict__ bh, float* __restrict__ out)
{
    const int g = (blockIdx.x * 256 + threadIdx.x) >> 6;
    const int lane = threadIdx.x & 63;
    if (g >= GG) return;
    const int b0 = gptr[g], b1 = gptr[g + 1];
    float s = 0.f;
    for (int i = b0 + lane; i < b1; i += 64) s += pernode[i];
    s += __shfl_xor(s, 1);
    s += __shfl_xor(s, 2);
    s += __shfl_xor(s, 4);
    s += __shfl_xor(s, 8);
    s += __shfl_xor(s, 16);
    s += __shfl_xor(s, 32);
    if (lane == 0) out[g] = s / fmaxf((float)(b1 - b0), 1.f) + bh[0];
}

// ---------------------------------------------------------------- launch
extern "C" void kernel_launch(void* const* d_in, const int* in_sizes, int n_in,
                              void* d_out, int out_size, void* d_ws, size_t ws_size,
                              hipStream_t stream)
{
    const float* x     = (const float*)d_in[0];
    const int*   edge  = (const int*)d_in[1];
    const int*   batch = (const int*)d_in[2];
    const int*   src   = edge;
    const int*   dst   = edge + N_EDGES;
    const float* Wh    = (const float*)d_in[21];
    const float* bh    = (const float*)d_in[22];
    float* out = (float*)d_out;

    const size_t N128 = (size_t)N_NODES * HD;
    float* buf_xl = (float*)d_ws;                       // N*128 f32
    float* buf_xr = buf_xl + N128;                      // N*128 f32
    unsigned short* Xh  = (unsigned short*)(buf_xr + N128);   // N*128 bf16
    unsigned short* Xl_ = Xh + N128;                    // N*128 bf16
    unsigned short* Wth = Xl_ + N128;                   // 3 * 256*128 bf16
    unsigned short* Wtl = Wth + 3 * 256 * 128;          // 3 * 256*128 bf16
    int* deg       = (int*)(Wtl + 3 * 256 * 128);       // N
    float* pernode = (float*)(deg + N_NODES);           // N
    int* rowptr  = (int*)(pernode + N_NODES);           // N+1
    int* cursor  = rowptr + N_NODES + 1;                // N
    int* csr_src = cursor + N_NODES;                    // E
    int* btot    = csr_src + N_EDGES;                   // NB
    int* gptr    = btot + NB;                           // G+1

    // ---- prep: memset deg, fused convert+hist+gptr, scan pair, scatter
    (void)hipMemsetAsync(deg, 0, (size_t)N_NODES * sizeof(int), stream);
    convert_prep<<<(NXV4 + NWCONV + N_EDGES + 256) / 256, 256, 0, stream>>>(
        x, Xh, Xl_,
        (const float*)d_in[3], (const float*)d_in[5],
        (const float*)d_in[9], (const float*)d_in[11],
        (const float*)d_in[15], (const float*)d_in[17],
        Wth, Wtl, dst, deg, batch, gptr);
    scan_block<<<NB, SCAN_B, 0, stream>>>(deg, rowptr, btot);
    scan_add<<<(N_NODES + 256) / 256, 256, 0, stream>>>(btot, rowptr, cursor);
    scatter_csr<<<(N_EDGES + 255) / 256, 256, 0, stream>>>(src, dst, cursor, csr_src);

    const int gemm_grid = 512;                 // 2 col-groups x 256 row streams
    const int attn_grid = (N_NODES + 3) / 4;

    for (int l = 0; l < 3; l++) {
        const float* bl  = (const float*)d_in[4 + 6 * l];
        const float* br  = (const float*)d_in[6 + 6 * l];
        const float* att = (const float*)d_in[7 + 6 * l];
        const float* bb  = (const float*)d_in[8 + 6 * l];

        if (l == 0)
            gemm_lds<64><<<gemm_grid, 256, 0, stream>>>(Xh, Xl_, Wth, Wtl,
                                                        bl, br, buf_xl, buf_xr, N_NODES);
        else
            gemm_lds<128><<<gemm_grid, 256, 0, stream>>>(Xh, Xl_,
                                                         Wth + l * 256 * 128, Wtl + l * 256 * 128,
                                                         bl, br, buf_xl, buf_xr, N_NODES);
        if (l < 2)
            node_attn<0><<<attn_grid, 256, 0, stream>>>(buf_xl, buf_xr, rowptr, csr_src,
                                                        att, bb, Xh, Xl_,
                                                        nullptr, nullptr);
        else
            node_attn<1><<<attn_grid, 256, 0, stream>>>(buf_xl, buf_xr, rowptr, csr_src,
                                                        att, bb, nullptr, nullptr,
                                                        Wh, pernode);
    }

    finish_head<<<GG / 4, 256, 0, stream>>>(pernode, gptr, bh, out);
}

// Round 19
// 433.786 us; speedup vs baseline: 1.0334x; 1.0334x over previous
//
#include <hip/hip_runtime.h>
#include <math.h>

#define N_NODES 50000
#define N_EDGES 800000
#define HD 128          // H*D = 4*32
#define GG 1024
#define NEG_SLOPE 0.2f
#define SCAN_B 1024
#define NB ((N_NODES + SCAN_B - 1) / SCAN_B)   // 49
#define NXV4 800000                            // x float4 count (N*64/4)
#define NWCONV 81920                           // W-convert thread count

typedef __attribute__((ext_vector_type(8))) short bf16x8;
typedef __attribute__((ext_vector_type(4))) float f32x4;
typedef __attribute__((ext_vector_type(2))) float f32x2;

__device__ __forceinline__ unsigned short f2bf(float v) {
    unsigned u = __float_as_uint(v);
    u += 0x7fff + ((u >> 16) & 1);       // round-to-nearest-even
    return (unsigned short)(u >> 16);
}
__device__ __forceinline__ float bf2f(unsigned short s) {
    return __uint_as_float((unsigned)s << 16);
}

// ------- fused conversions + deg-hist + gptr (deg zeroed by memset beforehand)
__global__ void convert_prep(const float* __restrict__ x,
                             unsigned short* __restrict__ Xh, unsigned short* __restrict__ Xl,
                             const float* __restrict__ W0l, const float* __restrict__ W0r,
                             const float* __restrict__ W1l, const float* __restrict__ W1r,
                             const float* __restrict__ W2l, const float* __restrict__ W2r,
                             unsigned short* __restrict__ Wth, unsigned short* __restrict__ Wtl,
                             const int* __restrict__ dst, int* __restrict__ deg,
                             const int* __restrict__ batch, int* __restrict__ gptr)
{
    const int i = blockIdx.x * 256 + threadIdx.x;
    if (i < NXV4) {
        const float4 v = *(const float4*)(x + (size_t)i * 4);
        ushort4 h, lo;
        h.x = f2bf(v.x); lo.x = f2bf(v.x - bf2f(h.x));
        h.y = f2bf(v.y); lo.y = f2bf(v.y - bf2f(h.y));
        h.z = f2bf(v.z); lo.z = f2bf(v.z - bf2f(h.z));
        h.w = f2bf(v.w); lo.w = f2bf(v.w - bf2f(h.w));
        *(ushort4*)(Xh + (size_t)i * 4) = h;
        *(ushort4*)(Xl + (size_t)i * 4) = lo;
        return;
    }
    if (i < NXV4 + NWCONV) {
        const int t = i - NXV4;
        const float* Wl; const float* Wr;
        int c, k, o;
        if (t < 16384) {                       // layer 0, K=64
            c = t >> 6; k = t & 63; o = t;
            Wl = W0l; Wr = W0r;
        } else if (t < 49152) {                // layer 1, K=128
            const int b = t - 16384; c = b >> 7; k = b & 127; o = 32768 + b;
            Wl = W1l; Wr = W1r;
        } else {                               // layer 2, K=128
            const int b = t - 49152; c = b >> 7; k = b & 127; o = 65536 + b;
            Wl = W2l; Wr = W2r;
        }
        const float v = (c < 128) ? Wl[(size_t)k * 128 + c] : Wr[(size_t)k * 128 + (c - 128)];
        const unsigned short hi = f2bf(v);
        Wth[o] = hi;
        Wtl[o] = f2bf(v - bf2f(hi));
        return;
    }
    const int e = i - NXV4 - NWCONV;
    if (e < N_EDGES) atomicAdd(&deg[dst[e]], 1);
    if (e > N_NODES) return;
    if (e == 0) {
        for (int g = 0; g <= batch[0]; g++) gptr[g] = 0;
    } else if (e == N_NODES) {
        for (int g = batch[N_NODES - 1] + 1; g <= GG; g++) gptr[g] = N_NODES;
    } else {
        const int b0 = batch[e - 1], b1 = batch[e];
        for (int g = b0 + 1; g <= b1; g++) gptr[g] = e;
    }
}

// ---------------------------------------------------------------- CSR scan
__launch_bounds__(SCAN_B)
__global__ void scan_block(const int* __restrict__ deg, int* __restrict__ rowptr,
                           int* __restrict__ btot)
{
    __shared__ int s[SCAN_B];
    const int tid = threadIdx.x;
    const int i = blockIdx.x * SCAN_B + tid;
    int v = (i < N_NODES) ? deg[i] : 0;
    s[tid] = v;
    __syncthreads();
    for (int off = 1; off < SCAN_B; off <<= 1) {
        int t = (tid >= off) ? s[tid - off] : 0;
        __syncthreads();
        s[tid] += t;
        __syncthreads();
    }
    if (i < N_NODES) rowptr[i] = s[tid] - v;
    if (tid == SCAN_B - 1) btot[blockIdx.x] = s[SCAN_B - 1];
}

__launch_bounds__(256)
__global__ void scan_add(const int* __restrict__ btot, int* __restrict__ rowptr,
                         int* __restrict__ cursor)
{
    __shared__ int sb[NB + 1];
    const int tid = threadIdx.x;
    if (tid < 64) {
        const int v = (tid < NB) ? btot[tid] : 0;
        int incl = v;
        #pragma unroll
        for (int off = 1; off < 64; off <<= 1) {
            const int t = __shfl_up(incl, off);
            if (tid >= off) incl += t;
        }
        if (tid < NB) sb[tid] = incl - v;      // exclusive prefix
        if (tid == NB - 1) sb[NB] = incl;      // total
    }
    __syncthreads();
    const int i = blockIdx.x * 256 + tid;
    if (i < N_NODES) {
        const int r = rowptr[i] + sb[i >> 10];
        rowptr[i] = r;
        cursor[i] = r;
    }
    if (i == N_NODES) rowptr[N_NODES] = sb[NB];
}

__global__ void scatter_csr(const int* __restrict__ src, const int* __restrict__ dst,
                            int* __restrict__ cursor, int* __restrict__ csr_src)
{
    int e = blockIdx.x * 256 + threadIdx.x;
    if (e >= N_EDGES) return;
    int pos = atomicAdd(&cursor[dst[e]], 1);
    csr_src[pos] = src[e];
}

// --------------------------------------------- persistent LDS-A MFMA dual GEMM
// (R11-proven config: 4 waves/block, 256 thr, grid 512 = 2 col-groups x 256 streams)
template<int K>
__launch_bounds__(256)
__global__ void gemm_lds(const unsigned short* __restrict__ Xh, const unsigned short* __restrict__ Xl,
                         const unsigned short* __restrict__ Wth, const unsigned short* __restrict__ Wtl,
                         const float* __restrict__ bl, const float* __restrict__ br,
                         float* __restrict__ Cl, float* __restrict__ Cr, int n)
{
    constexpr int NCH = K / 32;
    constexpr int STR = K + 8;
    constexpr int RT  = (N_NODES + 63) / 64;   // 782 row tiles
    __shared__ unsigned short AsH[64 * STR], AsL[64 * STR];
    const int tid  = threadIdx.x;
    const int wave = tid >> 6;
    const int lane = tid & 63;
    const int quad = lane >> 4;
    const int l15  = lane & 15;
    const int cg   = blockIdx.x & 1;           // col group
    const int rs   = blockIdx.x >> 1;          // row stream
    const int NS   = gridDim.x >> 1;
    const int colid = cg * 4 + wave;           // 0..7
    const int cb32  = colid * 32;

    // B fragments resident for the whole kernel
    bf16x8 Bh[NCH][2], Bo[NCH][2];
    #pragma unroll
    for (int ch = 0; ch < NCH; ch++)
        #pragma unroll
        for (int nt = 0; nt < 2; nt++) {
            const size_t wo = (size_t)(cb32 + nt * 16 + l15) * K + ch * 32 + quad * 8;
            Bh[ch][nt] = *(const bf16x8*)(Wth + wo);
            Bo[ch][nt] = *(const bf16x8*)(Wtl + wo);
        }

    const int cb = cb32 & 127;
    const float* bias = (colid < 4) ? bl : br;
    float* C = (colid < 4) ? Cl : Cr;
    const float bv0 = bias[cb + l15];
    const float bv1 = bias[cb + 16 + l15];

    for (int rt = rs; rt < RT; rt += NS) {
        const int row0 = rt * 64;
        // stage A tile: 64 rows x K (hi+lo), coalesced 16B per thread
        {
            constexpr int THR = K / 8;             // threads per row
            constexpr int RPP = 256 / THR;         // rows per pass
            const int sr = tid / THR, seg = tid % THR;
            #pragma unroll
            for (int ps = 0; ps < 64 / RPP; ps++) {
                const int r = ps * RPP + sr;
                int gr = row0 + r;
                gr = (gr < n) ? gr : (n - 1);      // clamp: dup rows never stored
                const size_t go = (size_t)gr * K + seg * 8;
                *(uint4*)&AsH[r * STR + seg * 8] = *(const uint4*)(Xh + go);
                *(uint4*)&AsL[r * STR + seg * 8] = *(const uint4*)(Xl + go);
            }
        }
        __syncthreads();

        f32x4 acc[4][2];
        #pragma unroll
        for (int mt = 0; mt < 4; mt++) {
            acc[mt][0] = (f32x4){0.f, 0.f, 0.f, 0.f};
            acc[mt][1] = (f32x4){0.f, 0.f, 0.f, 0.f};
        }
        #pragma unroll
        for (int ch = 0; ch < NCH; ch++) {
            bf16x8 ah[4], al[4];
            #pragma unroll
            for (int mt = 0; mt < 4; mt++) {
                ah[mt] = *(const bf16x8*)&AsH[(mt * 16 + l15) * STR + ch * 32 + quad * 8];
                al[mt] = *(const bf16x8*)&AsL[(mt * 16 + l15) * STR + ch * 32 + quad * 8];
            }
            #pragma unroll
            for (int nt = 0; nt < 2; nt++)
                #pragma unroll
                for (int mt = 0; mt < 4; mt++) {
                    acc[mt][nt] = __builtin_amdgcn_mfma_f32_16x16x32_bf16(ah[mt], Bh[ch][nt], acc[mt][nt], 0, 0, 0);
                    acc[mt][nt] = __builtin_amdgcn_mfma_f32_16x16x32_bf16(ah[mt], Bo[ch][nt], acc[mt][nt], 0, 0, 0);
                    acc[mt][nt] = __builtin_amdgcn_mfma_f32_16x16x32_bf16(al[mt], Bh[ch][nt], acc[mt][nt], 0, 0, 0);
                }
        }

        // epilogue: C/D layout col=lane&15, row=quad*4+reg [m89-verified]
        #pragma unroll
        for (int nt = 0; nt < 2; nt++) {
            const float bv = nt ? bv1 : bv0;
            #pragma unroll
            for (int mt = 0; mt < 4; mt++)
                #pragma unroll
                for (int r = 0; r < 4; r++) {
                    const int row = row0 + mt * 16 + quad * 4 + r;
                    if (row < n)
                        C[(size_t)row * 128 + cb + nt * 16 + l15] = acc[mt][nt][r] + bv;
                }
        }
        __syncthreads();    // LDS reuse fence before next stage
    }
}

// ------------------------------------------------- fused per-node attention
// one wave per dst node, FOUR edges in flight (4 groups x 16 lanes, 8 dims/lane).
// PER-HEAD softmax: head = 4-lane cluster; score reduce over xor 1,2 ONLY.
// Depth-1 prefetch, 32 VGPR, ~67% occupancy: measured local optimum
// (8-edge, depth-2, pk-asm variants all regressed -- R12/R18/R4).
// LAST=1: per-node h.Wh written to pernode[node] (plain store, no atomics).
template<int LAST>
__launch_bounds__(256)
__global__ void node_attn(const float* __restrict__ xl, const float* __restrict__ xr,
                          const int* __restrict__ rowptr, const int* __restrict__ csr_src,
                          const float* __restrict__ att, const float* __restrict__ bvec,
                          unsigned short* __restrict__ Hh, unsigned short* __restrict__ Hl,
                          const float* __restrict__ Wh, float* __restrict__ pernode)
{
    const int node = (blockIdx.x * 256 + threadIdx.x) >> 6;
    const int lane = threadIdx.x & 63;
    if (node >= N_NODES) return;
    const int grp = lane >> 4;     // 4 edge slots
    const int li  = lane & 15;     // 16 lanes per edge, 8 dims each; head = li>>2

    const size_t nb = (size_t)node * HD + li * 8;
    f32x2 xrp[4], awp[4];
    {
        const float4 a = *(const float4*)(xr + nb);
        const float4 b = *(const float4*)(xr + nb + 4);
        xrp[0] = (f32x2){a.x, a.y}; xrp[1] = (f32x2){a.z, a.w};
        xrp[2] = (f32x2){b.x, b.y}; xrp[3] = (f32x2){b.z, b.w};
        const float4 c = *(const float4*)(att + li * 8);
        const float4 d = *(const float4*)(att + li * 8 + 4);
        awp[0] = (f32x2){c.x, c.y}; awp[1] = (f32x2){c.z, c.w};
        awp[2] = (f32x2){d.x, d.y}; awp[3] = (f32x2){d.z, d.w};
    }
    const f32x2 nsl = (f32x2){NEG_SLOPE, NEG_SLOPE};
    const int beg = rowptr[node];
    const int end = rowptr[node + 1];

    float m = -1e30f, l = 0.f;
    f32x2 accp[4];
    #pragma unroll
    for (int j = 0; j < 4; j++) accp[j] = (f32x2){0.f, 0.f};

    // prologue gather
    f32x2 vp[4];
    {
        const int e0 = beg + grp;
        const int s0 = (e0 < end) ? csr_src[e0] : 0;
        const float4 a = *(const float4*)(xl + (size_t)s0 * HD + li * 8);
        const float4 b = *(const float4*)(xl + (size_t)s0 * HD + li * 8 + 4);
        vp[0] = (f32x2){a.x, a.y}; vp[1] = (f32x2){a.z, a.w};
        vp[2] = (f32x2){b.x, b.y}; vp[3] = (f32x2){b.z, b.w};
    }

    for (int base = beg; base < end; base += 4) {
        const bool valid = (base + grp) < end;
        f32x2 np[4];
        #pragma unroll
        for (int j = 0; j < 4; j++) np[j] = vp[j];
        if (base + 4 < end) {
            const int e2 = base + 4 + grp;
            const int s2 = (e2 < end) ? csr_src[e2] : 0;
            const float4 a = *(const float4*)(xl + (size_t)s2 * HD + li * 8);
            const float4 b = *(const float4*)(xl + (size_t)s2 * HD + li * 8 + 4);
            np[0] = (f32x2){a.x, a.y}; np[1] = (f32x2){a.z, a.w};
            np[2] = (f32x2){b.x, b.y}; np[3] = (f32x2){b.z, b.w};
        }
        // leaky_relu(v + xr) . att  -- two independent f32x2 chains
        f32x2 pd0 = (f32x2){0.f, 0.f}, pd1 = (f32x2){0.f, 0.f};
        #pragma unroll
        for (int j = 0; j < 4; j++) {
            f32x2 t = vp[j] + xrp[j];
            const f32x2 u = t * nsl;
            t[0] = fmaxf(t[0], u[0]);
            t[1] = fmaxf(t[1], u[1]);
            if (j & 1) pd1 = t * awp[j] + pd1;
            else       pd0 = t * awp[j] + pd0;
        }
        const f32x2 pds = pd0 + pd1;
        float p = pds[0] + pds[1];
        // per-head score: 4-lane cluster (32 dims) -> xor 1,2 only
        p += __shfl_xor(p, 1);
        p += __shfl_xor(p, 2);

        const float mn = valid ? fmaxf(m, p) : m;
        const float w  = valid ? __expf(p - mn) : 0.f;
        const float sc = __expf(m - mn);
        l = fmaf(l, sc, w);
        const f32x2 w2  = (f32x2){w, w};
        const f32x2 sc2 = (f32x2){sc, sc};
        #pragma unroll
        for (int j = 0; j < 4; j++) {
            accp[j] = accp[j] * sc2 + w2 * vp[j];
            vp[j] = np[j];
        }
        m = mn;
    }

    // cross-group merge (xor 16, then 32): same li (same head/dims), different group
    #pragma unroll
    for (int off = 16; off < 64; off <<= 1) {
        const float mo = __shfl_xor(m, off);
        const float lo = __shfl_xor(l, off);
        f32x2 bo[4];
        #pragma unroll
        for (int j = 0; j < 4; j++) {
            bo[j][0] = __shfl_xor(accp[j][0], off);
            bo[j][1] = __shfl_xor(accp[j][1], off);
        }
        const float mm = fmaxf(m, mo);
        const float e1 = __expf(m - mm);
        const float e2 = __expf(mo - mm);
        l = l * e1 + lo * e2;
        const f32x2 e1p = (f32x2){e1, e1};
        const f32x2 e2p = (f32x2){e2, e2};
        #pragma unroll
        for (int j = 0; j < 4; j++)
            accp[j] = accp[j] * e1p + bo[j] * e2p;
        m = mm;
    }

    if (grp == 0) {
        const float inv = (l > 0.f) ? 1.f / l : 0.f;   // per-head l (per lane)
        const float4 bb0 = *(const float4*)(bvec + li * 8);
        const float4 bb1 = *(const float4*)(bvec + li * 8 + 4);
        float o[8];
        o[0] = fmaf(accp[0][0], inv, bb0.x);
        o[1] = fmaf(accp[0][1], inv, bb0.y);
        o[2] = fmaf(accp[1][0], inv, bb0.z);
        o[3] = fmaf(accp[1][1], inv, bb0.w);
        o[4] = fmaf(accp[2][0], inv, bb1.x);
        o[5] = fmaf(accp[2][1], inv, bb1.y);
        o[6] = fmaf(accp[3][0], inv, bb1.z);
        o[7] = fmaf(accp[3][1], inv, bb1.w);
        #pragma unroll
        for (int j = 0; j < 8; j++)
            o[j] = (o[j] > 0.f) ? o[j] : expm1f(o[j]);
        if (LAST) {
            // fused head: d = h . Wh, deterministic per-node store (no atomics)
            const float4 w0 = *(const float4*)(Wh + li * 8);
            const float4 w1 = *(const float4*)(Wh + li * 8 + 4);
            float da = o[0] * w0.x + o[2] * w0.z;
            float db = o[1] * w0.y + o[3] * w0.w;
            da = fmaf(o[4], w1.x, da); db = fmaf(o[5], w1.y, db);
            da = fmaf(o[6], w1.z, da); db = fmaf(o[7], w1.w, db);
            float d = da + db;
            d += __shfl_xor(d, 1);
            d += __shfl_xor(d, 2);
            d += __shfl_xor(d, 4);
            d += __shfl_xor(d, 8);
            if (li == 0) pernode[node] = d;
        } else {
            bf16x8 hv, lv;
            #pragma unroll
            for (int j = 0; j < 8; j++) {
                unsigned short h = f2bf(o[j]);
                hv[j] = (short)h;
                lv[j] = (short)f2bf(o[j] - bf2f(h));
            }
            *(bf16x8*)(Hh + nb) = hv;
            *(bf16x8*)(Hl + nb) = lv;
        }
    }
}

// ------------------------------------------ head finish: one wave per graph
__launch_bounds__(256)
__global__ void finish_head(const float* __restrict__ pernode, const int* __restrict__ gptr,
                            const float* __restrict__ bh, float* __restrict__ out)
{
    const int g = (blockIdx.x * 256 + threadIdx.x) >> 6;
    const int lane = threadIdx.x & 63;
    if (g >= GG) return;
    const int b0 = gptr[g], b1 = gptr[g + 1];
    float s = 0.f;
    for (int i = b0 + lane; i < b1; i += 64) s += pernode[i];
    s += __shfl_xor(s, 1);
    s += __shfl_xor(s, 2);
    s += __shfl_xor(s, 4);
    s += __shfl_xor(s, 8);
    s += __shfl_xor(s, 16);
    s += __shfl_xor(s, 32);
    if (lane == 0) out[g] = s / fmaxf((float)(b1 - b0), 1.f) + bh[0];
}

// ---------------------------------------------------------------- launch
extern "C" void kernel_launch(void* const* d_in, const int* in_sizes, int n_in,
                              void* d_out, int out_size, void* d_ws, size_t ws_size,
                              hipStream_t stream)
{
    const float* x     = (const float*)d_in[0];
    const int*   edge  = (const int*)d_in[1];
    const int*   batch = (const int*)d_in[2];
    const int*   src   = edge;
    const int*   dst   = edge + N_EDGES;
    const float* Wh    = (const float*)d_in[21];
    const float* bh    = (const float*)d_in[22];
    float* out = (float*)d_out;

    const size_t N128 = (size_t)N_NODES * HD;
    float* buf_xl = (float*)d_ws;                       // N*128 f32
    float* buf_xr = buf_xl + N128;                      // N*128 f32
    unsigned short* Xh  = (unsigned short*)(buf_xr + N128);   // N*128 bf16
    unsigned short* Xl_ = Xh + N128;                    // N*128 bf16
    unsigned short* Wth = Xl_ + N128;                   // 3 * 256*128 bf16
    unsigned short* Wtl = Wth + 3 * 256 * 128;          // 3 * 256*128 bf16
    int* deg       = (int*)(Wtl + 3 * 256 * 128);       // N
    float* pernode = (float*)(deg + N_NODES);           // N
    int* rowptr  = (int*)(pernode + N_NODES);           // N+1
    int* cursor  = rowptr + N_NODES + 1;                // N
    int* csr_src = cursor + N_NODES;                    // E
    int* btot    = csr_src + N_EDGES;                   // NB
    int* gptr    = btot + NB;                           // G+1

    // ---- prep: memset deg, fused convert+hist+gptr, scan pair, scatter
    (void)hipMemsetAsync(deg, 0, (size_t)N_NODES * sizeof(int), stream);
    convert_prep<<<(NXV4 + NWCONV + N_EDGES + 256) / 256, 256, 0, stream>>>(
        x, Xh, Xl_,
        (const float*)d_in[3], (const float*)d_in[5],
        (const float*)d_in[9], (const float*)d_in[11],
        (const float*)d_in[15], (const float*)d_in[17],
        Wth, Wtl, dst, deg, batch, gptr);
    scan_block<<<NB, SCAN_B, 0, stream>>>(deg, rowptr, btot);
    scan_add<<<(N_NODES + 256) / 256, 256, 0, stream>>>(btot, rowptr, cursor);
    scatter_csr<<<(N_EDGES + 255) / 256, 256, 0, stream>>>(src, dst, cursor, csr_src);

    const int gemm_grid = 512;                 // 2 col-groups x 256 row streams
    const int attn_grid = (N_NODES + 3) / 4;

    for (int l = 0; l < 3; l++) {
        const float* bl  = (const float*)d_in[4 + 6 * l];
        const float* br  = (const float*)d_in[6 + 6 * l];
        const float* att = (const float*)d_in[7 + 6 * l];
        const float* bb  = (const float*)d_in[8 + 6 * l];

        if (l == 0)
            gemm_lds<64><<<gemm_grid, 256, 0, stream>>>(Xh, Xl_, Wth, Wtl,
                                                        bl, br, buf_xl, buf_xr, N_NODES);
        else
            gemm_lds<128><<<gemm_grid, 256, 0, stream>>>(Xh, Xl_,
                                                         Wth + l * 256 * 128, Wtl + l * 256 * 128,
                                                         bl, br, buf_xl, buf_xr, N_NODES);
        if (l < 2)
            node_attn<0><<<attn_grid, 256, 0, stream>>>(buf_xl, buf_xr, rowptr, csr_src,
                                                        att, bb, Xh, Xl_,
                                                        nullptr, nullptr);
        else
            node_attn<1><<<attn_grid, 256, 0, stream>>>(buf_xl, buf_xr, rowptr, csr_src,
                                                        att, bb, nullptr, nullptr,
                                                        Wh, pernode);
    }

    finish_head<<<GG / 4, 256, 0, stream>>>(pernode, gptr, bh, out);
}